// Round 7
// baseline (444.785 us; speedup 1.0000x reference)
//
#include <hip/hip_runtime.h>
#include <hip/hip_bf16.h>
#include <math.h>

#define G_HID 16
#define S_HID 10
#define D 128
#define MAX_STEP 4
#define NEG 0.01f
#define SCAN_TILE 1024
#define YT_PITCH 170   // bf16 elems; 85 words, stride 85%32=21 coprime-ish -> 2-way banks

typedef __attribute__((ext_vector_type(8))) short short8;
typedef __attribute__((ext_vector_type(4))) float f32x4;

__device__ __forceinline__ float leaky_f(float v){ return v >= 0.f ? v : NEG*v; }
__device__ __forceinline__ unsigned short f2bf(float f){
    unsigned int u = __float_as_uint(f);
    u = (u + 0x7FFFu + ((u>>16)&1u)) >> 16;
    return (unsigned short)u;
}
__device__ __forceinline__ float bf_lo(unsigned int v){ return __uint_as_float(v << 16); }
__device__ __forceinline__ float bf_hi(unsigned int v){ return __uint_as_float(v & 0xFFFF0000u); }

// ---------------- prep: A, A^2, A^3 (f32) + zpack of z0 (MFMA A-frag layout) ----------------
__global__ void prep_kernel(const float* __restrict__ hidden_adj,   // [16][45]
                            const float* __restrict__ hidden_feat,  // [16][10][128]
                            short* __restrict__ zpack,              // [10][4][64][8]
                            float* __restrict__ Ai)                 // [3][16][10][10]
{
    int g = blockIdx.x;
    __shared__ float Ag[S_HID][S_HID];
    __shared__ float A2[S_HID][S_HID];
    int t = threadIdx.x;  // 128
    if (t < S_HID*S_HID) {
        int i = t / S_HID, j = t % S_HID;
        float v = 0.f;
        if (i < j) {
            int idx = 9*i - i*(i-1)/2 + (j - i - 1);
            v = leaky_f(hidden_adj[g*45 + idx]);
        } else if (i > j) {
            int idx = 9*j - j*(j-1)/2 + (i - j - 1);
            v = leaky_f(hidden_adj[g*45 + idx]);
        }
        Ag[i][j] = v;
    }
    __syncthreads();
    if (t < 100){
        int s = t/10, u = t%10;
        float c = 0.f;
        #pragma unroll
        for (int w = 0; w < 10; ++w) c += Ag[s][w]*Ag[w][u];
        A2[s][u] = c;
        Ai[0*1600 + g*100 + t] = Ag[s][u];
    }
    __syncthreads();
    if (t < 100){
        int s = t/10, u = t%10;
        float c = 0.f;
        #pragma unroll
        for (int w = 0; w < 10; ++w) c += A2[s][w]*Ag[w][u];
        Ai[1*1600 + g*100 + t] = A2[s][u];
        Ai[2*1600 + g*100 + t] = c;
    }
    for (int idx = t; idx < S_HID*D; idx += 128) {
        int s = idx / D, k = idx % D;
        int row = g*S_HID + s;
        int tt = row >> 4, li = row & 15;
        int kt = k >> 5, q = (k >> 3) & 3, j = k & 7;
        zpack[((tt*4 + kt)*64 + q*16 + li)*8 + j] = (short)f2bf(hidden_feat[(g*S_HID + s)*D + k]);
    }
}

// ---------------- pack fc_w into MFMA B-fragment layout ----------------
__global__ void wpack_kernel(const float* __restrict__ fc_w, short* __restrict__ wp){
    int idx = blockIdx.x*256 + threadIdx.x;
    if (idx >= 16384) return;
    int j = idx & 7, lane = (idx >> 3) & 63, ctkt = idx >> 9;
    int ct = ctkt & 7, kt = ctkt >> 3;
    int k   = kt*32 + (lane >> 4)*8 + j;
    int col = ct*16 + (lane & 15);
    wp[idx] = (short)f2bf(fc_w[k*D + col]);
}

// ---------------- CSR build ----------------
__global__ void count_kernel(const int* __restrict__ dst, int* __restrict__ offsets,
                             int* __restrict__ rnk, int E){
    int e0 = (blockIdx.x*blockDim.x + threadIdx.x)*4;
    if (e0 >= E) return;
    if (e0 + 4 <= E){
        int4 d = *reinterpret_cast<const int4*>(&dst[e0]);
        int r0 = atomicAdd(&offsets[d.x+1], 1);
        int r1 = atomicAdd(&offsets[d.y+1], 1);
        int r2 = atomicAdd(&offsets[d.z+1], 1);
        int r3 = atomicAdd(&offsets[d.w+1], 1);
        *reinterpret_cast<int4*>(&rnk[e0]) = make_int4(r0,r1,r2,r3);
    } else {
        for (int e = e0; e < E; ++e) rnk[e] = atomicAdd(&offsets[dst[e]+1], 1);
    }
}

__global__ void scan1_kernel(int* __restrict__ data, int* __restrict__ bsums, int n){
    __shared__ int wsum[4];
    int base = blockIdx.x * SCAN_TILE + threadIdx.x*4;
    int v[4];
    #pragma unroll
    for (int j=0;j<4;++j) v[j] = (base+j < n) ? data[base+j] : 0;
    v[1]+=v[0]; v[2]+=v[1]; v[3]+=v[2];
    int lane = threadIdx.x & 63;
    int w = threadIdx.x >> 6;
    int s = v[3];
    for (int d=1; d<64; d<<=1){
        int o = __shfl_up(s, d);
        if (lane >= d) s += o;
    }
    if (lane == 63) wsum[w] = s;
    int sexc = s - v[3];
    __syncthreads();
    int woff = 0;
    for (int ww=0; ww<w; ++ww) woff += wsum[ww];
    int off = woff + sexc;
    #pragma unroll
    for (int j=0;j<4;++j) { if (base+j < n) data[base+j] = v[j] + off; }
    if (threadIdx.x == 255) bsums[blockIdx.x] = off + v[3];
}

__global__ void scan2_kernel(int* __restrict__ bsums, int nb){
    __shared__ int ws[4];
    __shared__ int carry_s;
    if (threadIdx.x == 0) carry_s = 0;
    __syncthreads();
    for (int start = 0; start < nb; start += 256){
        int i = start + (int)threadIdx.x;
        int v = (i < nb) ? bsums[i] : 0;
        int lane = threadIdx.x & 63, w = threadIdx.x >> 6;
        int s = v;
        for (int d=1; d<64; d<<=1){ int o = __shfl_up(s, d); if (lane >= d) s += o; }
        if (lane == 63) ws[w] = s;
        __syncthreads();
        int woff = 0;
        for (int ww=0; ww<w; ++ww) woff += ws[ww];
        int inc = s + woff + carry_s;
        if (i < nb) bsums[i] = inc - v;
        __syncthreads();
        if (threadIdx.x == 255) carry_s = inc;
        __syncthreads();
    }
}

__global__ void scan3_kernel(int* __restrict__ data, const int* __restrict__ bsums, int n){
    int base = blockIdx.x * SCAN_TILE + threadIdx.x*4;
    int add = bsums[blockIdx.x];
    #pragma unroll
    for (int j=0;j<4;++j){ if (base+j < n) data[base+j] += add; }
}

__global__ void fill_kernel(const int* __restrict__ src, const int* __restrict__ dst,
                            const int* __restrict__ rnk, const int* __restrict__ offsets,
                            int* __restrict__ csr, int E){
    int e0 = (blockIdx.x*blockDim.x + threadIdx.x)*4;
    if (e0 >= E) return;
    if (e0 + 4 <= E){
        int4 d = *reinterpret_cast<const int4*>(&dst[e0]);
        int4 r = *reinterpret_cast<const int4*>(&rnk[e0]);
        int4 s = *reinterpret_cast<const int4*>(&src[e0]);
        int o0 = offsets[d.x], o1 = offsets[d.y], o2 = offsets[d.z], o3 = offsets[d.w];
        csr[o0 + r.x] = s.x;
        csr[o1 + r.y] = s.y;
        csr[o2 + r.z] = s.z;
        csr[o3 + r.w] = s.w;
    } else {
        for (int e = e0; e < E; ++e) csr[offsets[dst[e]] + rnk[e]] = src[e];
    }
}

// ======== helpers ========
__device__ __forceinline__ void compute_slots(const int* __restrict__ batch, int n0, int N,
                                              int* slots, int* slotb, int* nslots_s, int t){
    if (t < 64) {
        int gn = n0 + t;
        int b = (gn < N) ? batch[gn] : -1;
        int bprev = -1;
        if (t > 0) bprev = (gn-1 < N) ? batch[gn-1] : -1;
        int flag = (t == 0 || b != bprev) ? 1 : 0;
        int s = flag;
        for (int d=1; d<64; d<<=1){ int o = __shfl_up(s, d); if (t >= d) s += o; }
        int slot = s - 1;
        slots[t] = slot;
        if (flag) slotb[slot] = b;
        if (t == 63) *nslots_s = s;
    }
}

// ---------------- fused: embed + fc MFMA + sigmoid + Y0 + self-dot + W0/U1..U3 write ----------------
// W0,U stored per node as q = s*16+g (bf16)
__global__ __launch_bounds__(256) void embed_step0_kernel(
        const int* __restrict__ x_idx, const float* __restrict__ poi_emb,
        const short* __restrict__ wp, const float* __restrict__ fc_b,
        const short* __restrict__ zpack, const int* __restrict__ batch,
        const float* __restrict__ Ai,
        unsigned short* __restrict__ W0, unsigned short* __restrict__ U,
        unsigned long long uslice,
        float* __restrict__ pooled, int N)
{
    __shared__ __align__(16) char lbuf[64*YT_PITCH*2];  // xs[64][136] bf16, then ytr[64][170]
    __shared__ float accs[64][G_HID];
    __shared__ int slots[64];
    __shared__ int slotb[64];
    __shared__ int nslots_s;
    unsigned short* xs  = (unsigned short*)lbuf;
    unsigned short* ytr = (unsigned short*)lbuf;
    int n0 = blockIdx.x * 64;
    int t = threadIdx.x;  // 256

    #pragma unroll
    for (int i = 0; i < 8; ++i) {
        int idx = t + i*256;
        int row = idx >> 5, c4 = (idx & 31)*4;
        int gn = n0 + row;
        float4 v = make_float4(0.f,0.f,0.f,0.f);
        if (gn < N) v = *reinterpret_cast<const float4*>(&poi_emb[(size_t)x_idx[gn]*D + c4]);
        unsigned int p0 = (unsigned int)f2bf(v.x) | ((unsigned int)f2bf(v.y) << 16);
        unsigned int p1 = (unsigned int)f2bf(v.z) | ((unsigned int)f2bf(v.w) << 16);
        *reinterpret_cast<uint2*>(&xs[row*136 + c4]) = make_uint2(p0, p1);
    }
    for (int idx = t; idx < 64*G_HID; idx += 256) ((float*)accs)[idx] = 0.f;
    compute_slots(batch, n0, N, slots, slotb, &nslots_s, t);
    __syncthreads();

    int l = t & 63, w = t >> 6, li = l & 15, q = l >> 4;
    short8 a[4];
    #pragma unroll
    for (int kt = 0; kt < 4; ++kt)
        a[kt] = *reinterpret_cast<const short8*>(&xs[(w*16 + li)*136 + kt*32 + q*8]);
    f32x4 facc[8];
    #pragma unroll
    for (int ct = 0; ct < 8; ++ct) facc[ct] = (f32x4){0.f,0.f,0.f,0.f};
    #pragma unroll
    for (int kt = 0; kt < 4; ++kt){
        #pragma unroll
        for (int ct = 0; ct < 8; ++ct){
            short8 b = reinterpret_cast<const short8*>(wp)[(kt*8 + ct)*64 + l];
            facc[ct] = __builtin_amdgcn_mfma_f32_16x16x32_bf16(a[kt], b, facc[ct], 0, 0, 0);
        }
    }
    #pragma unroll
    for (int ct = 0; ct < 8; ++ct){
        float bias = fc_b[ct*16 + li];
        #pragma unroll
        for (int r = 0; r < 4; ++r){
            int row = w*16 + q*4 + r;
            float s = (n0 + row < N) ? 1.f/(1.f + __expf(-(facc[ct][r] + bias))) : 0.f;
            xs[row*136 + ct*16 + li] = f2bf(s);
        }
    }
    __syncthreads();
    short8 bw[4];
    #pragma unroll
    for (int kt = 0; kt < 4; ++kt)
        bw[kt] = *reinterpret_cast<const short8*>(&xs[(w*16 + li)*136 + kt*32 + q*8]);
    __syncthreads();

    // Y0 = Z0 X^T -> transposed bf16 in ytr[node][g*10+s]
    #pragma unroll
    for (int t10 = 0; t10 < 10; ++t10){
        f32x4 acc = (f32x4){0.f,0.f,0.f,0.f};
        #pragma unroll
        for (int kt = 0; kt < 4; ++kt){
            short8 az = *reinterpret_cast<const short8*>(&zpack[((t10*4 + kt)*64 + l)*8]);
            acc = __builtin_amdgcn_mfma_f32_16x16x32_bf16(az, bw[kt], acc, 0, 0, 0);
        }
        int base = (w*16 + li)*YT_PITCH + t10*16 + q*4;
        *reinterpret_cast<unsigned int*>(&ytr[base])   =
            (unsigned int)f2bf(acc[0]) | ((unsigned int)f2bf(acc[1]) << 16);
        *reinterpret_cast<unsigned int*>(&ytr[base+2]) =
            (unsigned int)f2bf(acc[2]) | ((unsigned int)f2bf(acc[3]) << 16);
    }
    __syncthreads();

    // W0 (rq=0) and U1..U3 (rq=1..3) writes in [s*16+g] layout
    {
        int nd = t & 63, rq = t >> 6, gn2 = n0 + nd;
        if (gn2 < N){
            if (rq == 0){
                unsigned int* wrow = reinterpret_cast<unsigned int*>(W0 + (size_t)gn2*160);
                #pragma unroll
                for (int s = 0; s < 10; ++s){
                    #pragma unroll
                    for (int gp = 0; gp < 8; ++gp){
                        unsigned int lo = ytr[nd*YT_PITCH + (2*gp)*10 + s];
                        unsigned int hi = ytr[nd*YT_PITCH + (2*gp+1)*10 + s];
                        wrow[s*8 + gp] = lo | (hi << 16);
                    }
                }
            } else {
                const float* Aw = Ai + (size_t)(rq-1)*1600;
                unsigned int* urow = reinterpret_cast<unsigned int*>(
                    U + (size_t)(rq-1)*uslice + (size_t)gn2*160);
                for (int gp = 0; gp < 8; ++gp){
                    float ya[10], yb[10];
                    #pragma unroll
                    for (int tt = 0; tt < 5; ++tt){
                        unsigned int pa = *reinterpret_cast<const unsigned int*>(
                            &ytr[nd*YT_PITCH + (2*gp)*10 + 2*tt]);
                        unsigned int pb = *reinterpret_cast<const unsigned int*>(
                            &ytr[nd*YT_PITCH + (2*gp+1)*10 + 2*tt]);
                        ya[2*tt] = bf_lo(pa); ya[2*tt+1] = bf_hi(pa);
                        yb[2*tt] = bf_lo(pb); yb[2*tt+1] = bf_hi(pb);
                    }
                    #pragma unroll
                    for (int s = 0; s < 10; ++s){
                        float ua = 0.f, ub = 0.f;
                        #pragma unroll
                        for (int tt = 0; tt < 10; ++tt){
                            ua += Aw[(2*gp)*100   + s*10 + tt] * ya[tt];
                            ub += Aw[(2*gp+1)*100 + s*10 + tt] * yb[tt];
                        }
                        urow[s*8 + gp] = (unsigned int)f2bf(ua) | ((unsigned int)f2bf(ub) << 16);
                    }
                }
            }
        }
    }
    // self-dot d0[g,node] -> slot pooling
    #pragma unroll
    for (int i = 0; i < 4; ++i){
        int nd2 = t & 63;
        int g = (t >> 6) + i*4;
        if (n0 + nd2 < N){
            float c = 0.f;
            #pragma unroll
            for (int s = 0; s < S_HID; ++s){
                float y = bf_lo((unsigned int)ytr[nd2*YT_PITCH + g*10 + s]);
                c += y*y;
            }
            atomicAdd(&accs[slots[nd2]][g], c);
        }
    }
    __syncthreads();
    int ns = nslots_s;
    for (int idx = t; idx < ns*G_HID; idx += 256){
        int j = idx >> 4, g = idx & 15;
        int b = slotb[j];
        if (b >= 0) atomicAdd(&pooled[(size_t)b*64 + g], accs[j][g]);
    }
}

// ---------------- per-step: W_i = prop(W_{i-1}); d = <U_i, W_i>; pool (LDS-free) ----------------
__global__ __launch_bounds__(256) void propw_kernel(
        const uint2* __restrict__ Win, uint2* __restrict__ Wout,
        const uint2* __restrict__ Ui,
        const int* __restrict__ offsets, const int* __restrict__ csr,
        const int* __restrict__ batch, float* __restrict__ pooled,
        int N, int stepoff)
{
    int t = threadIdx.x;
    int wv = t >> 6, l = t & 63;
    int v = blockIdx.x*4 + wv;
    if (v >= N) return;
    int beg = offsets[v], end = offsets[v+1];
    int lc = min(l, 39);
    float a0=0.f, a1=0.f, a2=0.f, a3=0.f;
    for (int base = beg; base < end; base += 64){
        int cnt = min(64, end - base);
        int myu = (base + l < end) ? csr[base + l] : 0;
        for (int ei = 0; ei < cnt; ei += 4){
            int u0 = __shfl(myu, ei);
            int u1 = __shfl(myu, (ei+1)&63);
            int u2 = __shfl(myu, (ei+2)&63);
            int u3 = __shfl(myu, (ei+3)&63);
            uint2 w0 = Win[(size_t)u0*40 + lc];
            uint2 w1 = Win[(size_t)u1*40 + lc];
            uint2 w2 = Win[(size_t)u2*40 + lc];
            uint2 w3 = Win[(size_t)u3*40 + lc];
            if (ei+1 >= cnt){ w1.x = 0u; w1.y = 0u; }
            if (ei+2 >= cnt){ w2.x = 0u; w2.y = 0u; }
            if (ei+3 >= cnt){ w3.x = 0u; w3.y = 0u; }
            a0 += bf_lo(w0.x) + bf_lo(w1.x) + bf_lo(w2.x) + bf_lo(w3.x);
            a1 += bf_hi(w0.x) + bf_hi(w1.x) + bf_hi(w2.x) + bf_hi(w3.x);
            a2 += bf_lo(w0.y) + bf_lo(w1.y) + bf_lo(w2.y) + bf_lo(w3.y);
            a3 += bf_hi(w0.y) + bf_hi(w1.y) + bf_hi(w2.y) + bf_hi(w3.y);
        }
    }
    uint2 uv = Ui[(size_t)v*40 + lc];
    bool act = (l < 40);
    float c0 = act ? a0*bf_lo(uv.x) : 0.f;
    float c1 = act ? a1*bf_hi(uv.x) : 0.f;
    float c2 = act ? a2*bf_lo(uv.y) : 0.f;
    float c3 = act ? a3*bf_hi(uv.y) : 0.f;
    if (act){
        uint2 o;
        o.x = (unsigned int)f2bf(a0) | ((unsigned int)f2bf(a1) << 16);
        o.y = (unsigned int)f2bf(a2) | ((unsigned int)f2bf(a3) << 16);
        Wout[(size_t)v*40 + l] = o;
    }
    #pragma unroll
    for (int m = 4; m <= 32; m <<= 1){
        c0 += __shfl_xor(c0, m);
        c1 += __shfl_xor(c1, m);
        c2 += __shfl_xor(c2, m);
        c3 += __shfl_xor(c3, m);
    }
    if (l < 4){
        int b = batch[v];
        float* pb = &pooled[(size_t)b*64 + stepoff + 4*l];
        atomicAdd(pb+0, c0);
        atomicAdd(pb+1, c1);
        atomicAdd(pb+2, c2);
        atomicAdd(pb+3, c3);
    }
}

// ---------------- out = leaky(pooled @ mlp_w + mlp_b) ----------------
__global__ void out_kernel(const float* __restrict__ pooled, const float* __restrict__ mlp_w,
                           const float* __restrict__ mlp_b, float* __restrict__ out, int B){
    __shared__ float row[64];
    int b = blockIdx.x;
    int t = threadIdx.x;  // 128
    if (t < 64) row[t] = pooled[(size_t)b*64 + t];
    __syncthreads();
    float acc = mlp_b[t];
    for (int j=0;j<64;++j) acc += row[j]*mlp_w[j*D + t];
    out[(size_t)b*D + t] = leaky_f(acc);
}

extern "C" void kernel_launch(void* const* d_in, const int* in_sizes, int n_in,
                              void* d_out, int out_size, void* d_ws, size_t ws_size,
                              hipStream_t stream)
{
    const int*   x_idx = (const int*)d_in[0];
    const int*   edge  = (const int*)d_in[1];
    const int*   batch = (const int*)d_in[2];
    const float* poi   = (const float*)d_in[3];
    const float* fc_w  = (const float*)d_in[4];
    const float* fc_b  = (const float*)d_in[5];
    const float* adj   = (const float*)d_in[6];
    const float* feat  = (const float*)d_in[7];
    const float* mlp_w = (const float*)d_in[8];
    const float* mlp_b = (const float*)d_in[9];
    float* out = (float*)d_out;

    int N = in_sizes[0];
    int E = in_sizes[1] / 2;
    int B = out_size / D;
    int sblk = (N + 63) / 64;
    size_t NP = (size_t)sblk * 64;

    char* p = (char*)d_ws;
    auto alloc = [&](size_t bytes)->char* {
        char* r = p;
        p += (bytes + 255) & ~(size_t)255;
        return r;
    };
    unsigned short* W0 = (unsigned short*)alloc(NP*160*2);
    unsigned short* Wa = (unsigned short*)alloc(NP*160*2);
    unsigned short* Wb = (unsigned short*)alloc(NP*160*2);
    unsigned short* U  = (unsigned short*)alloc((size_t)3*NP*160*2);
    float* pooled      = (float*)alloc((size_t)B*64*4);
    short* zpack       = (short*)alloc((size_t)20480*2);
    short* wp          = (short*)alloc((size_t)16384*2);
    float* Ai          = (float*)alloc((size_t)3*1600*4);
    int*   offsets     = (int*)alloc((size_t)(N+1)*4);
    int*   rnk         = (int*)alloc((size_t)E*4);
    int*   csr         = (int*)alloc((size_t)E*4);
    int*   bsums       = (int*)alloc(4096);

    const int* srcp = edge;
    const int* dstp = edge + E;

    hipMemsetAsync(offsets, 0, (size_t)(N+1)*4, stream);
    hipMemsetAsync(pooled, 0, (size_t)B*64*4, stream);

    prep_kernel<<<G_HID, 128, 0, stream>>>(adj, feat, zpack, Ai);
    wpack_kernel<<<64, 256, 0, stream>>>(fc_w, wp);

    count_kernel<<<(E/4 + 255)/256, 256, 0, stream>>>(dstp, offsets, rnk, E);
    int scan_n = N + 1;
    int nblk = (scan_n + SCAN_TILE - 1) / SCAN_TILE;
    scan1_kernel<<<nblk, 256, 0, stream>>>(offsets, bsums, scan_n);
    scan2_kernel<<<1, 256, 0, stream>>>(bsums, nblk);
    scan3_kernel<<<nblk, 256, 0, stream>>>(offsets, bsums, scan_n);
    fill_kernel<<<(E/4 + 255)/256, 256, 0, stream>>>(srcp, dstp, rnk, offsets, csr, E);

    embed_step0_kernel<<<sblk, 256, 0, stream>>>(x_idx, poi, wp, fc_b, zpack, batch,
                                                 Ai, W0, U, (unsigned long long)(NP*160),
                                                 pooled, N);

    const unsigned short* win = W0;
    unsigned short* bufs[2] = {Wa, Wb};
    for (int i = 1; i < MAX_STEP; ++i){
        unsigned short* wout = bufs[(i-1) & 1];
        propw_kernel<<<(N+3)/4, 256, 0, stream>>>(
            (const uint2*)win, (uint2*)wout,
            (const uint2*)(U + (size_t)(i-1)*NP*160),
            offsets, csr, batch, pooled, N, i*G_HID);
        win = wout;
    }
    out_kernel<<<B, D, 0, stream>>>(pooled, mlp_w, mlp_b, out, B);
}

// Round 8
// 414.423 us; speedup vs baseline: 1.0733x; 1.0733x over previous
//
#include <hip/hip_runtime.h>
#include <hip/hip_bf16.h>
#include <math.h>

#define G_HID 16
#define S_HID 10
#define D 128
#define MAX_STEP 4
#define NEG 0.01f
#define SCAN_TILE 1024
#define YT_PITCH 170   // bf16 elems; 85 dwords, 85%32=21 -> near-conflict-free
#define UB_PITCH 164   // bf16 elems; 82 dwords, row = 328B (8B aligned)

typedef __attribute__((ext_vector_type(8))) short short8;
typedef __attribute__((ext_vector_type(4))) float f32x4;

__device__ __forceinline__ float leaky_f(float v){ return v >= 0.f ? v : NEG*v; }
__device__ __forceinline__ unsigned short f2bf(float f){
    unsigned int u = __float_as_uint(f);
    u = (u + 0x7FFFu + ((u>>16)&1u)) >> 16;
    return (unsigned short)u;
}
__device__ __forceinline__ float bf_lo(unsigned int v){ return __uint_as_float(v << 16); }
__device__ __forceinline__ float bf_hi(unsigned int v){ return __uint_as_float(v & 0xFFFF0000u); }

// ---------------- prep: A, A^2, A^3 (f32) + zpack of z0 (MFMA A-frag layout) ----------------
__global__ void prep_kernel(const float* __restrict__ hidden_adj,   // [16][45]
                            const float* __restrict__ hidden_feat,  // [16][10][128]
                            short* __restrict__ zpack,              // [10][4][64][8]
                            float* __restrict__ Ai)                 // [3][16][10][10]
{
    int g = blockIdx.x;
    __shared__ float Ag[S_HID][S_HID];
    __shared__ float A2[S_HID][S_HID];
    int t = threadIdx.x;  // 128
    if (t < S_HID*S_HID) {
        int i = t / S_HID, j = t % S_HID;
        float v = 0.f;
        if (i < j) {
            int idx = 9*i - i*(i-1)/2 + (j - i - 1);
            v = leaky_f(hidden_adj[g*45 + idx]);
        } else if (i > j) {
            int idx = 9*j - j*(j-1)/2 + (i - j - 1);
            v = leaky_f(hidden_adj[g*45 + idx]);
        }
        Ag[i][j] = v;
    }
    __syncthreads();
    if (t < 100){
        int s = t/10, u = t%10;
        float c = 0.f;
        #pragma unroll
        for (int w = 0; w < 10; ++w) c += Ag[s][w]*Ag[w][u];
        A2[s][u] = c;
        Ai[0*1600 + g*100 + t] = Ag[s][u];
    }
    __syncthreads();
    if (t < 100){
        int s = t/10, u = t%10;
        float c = 0.f;
        #pragma unroll
        for (int w = 0; w < 10; ++w) c += A2[s][w]*Ag[w][u];
        Ai[1*1600 + g*100 + t] = A2[s][u];
        Ai[2*1600 + g*100 + t] = c;
    }
    for (int idx = t; idx < S_HID*D; idx += 128) {
        int s = idx / D, k = idx % D;
        int row = g*S_HID + s;
        int tt = row >> 4, li = row & 15;
        int kt = k >> 5, q = (k >> 3) & 3, j = k & 7;
        zpack[((tt*4 + kt)*64 + q*16 + li)*8 + j] = (short)f2bf(hidden_feat[(g*S_HID + s)*D + k]);
    }
}

// ---------------- pack fc_w into MFMA B-fragment layout ----------------
__global__ void wpack_kernel(const float* __restrict__ fc_w, short* __restrict__ wp){
    int idx = blockIdx.x*256 + threadIdx.x;
    if (idx >= 16384) return;
    int j = idx & 7, lane = (idx >> 3) & 63, ctkt = idx >> 9;
    int ct = ctkt & 7, kt = ctkt >> 3;
    int k   = kt*32 + (lane >> 4)*8 + j;
    int col = ct*16 + (lane & 15);
    wp[idx] = (short)f2bf(fc_w[k*D + col]);
}

// ---------------- CSR build ----------------
__global__ void count_kernel(const int* __restrict__ dst, int* __restrict__ offsets,
                             int* __restrict__ rnk, int E){
    int e0 = (blockIdx.x*blockDim.x + threadIdx.x)*4;
    if (e0 >= E) return;
    if (e0 + 4 <= E){
        int4 d = *reinterpret_cast<const int4*>(&dst[e0]);
        int r0 = atomicAdd(&offsets[d.x+1], 1);
        int r1 = atomicAdd(&offsets[d.y+1], 1);
        int r2 = atomicAdd(&offsets[d.z+1], 1);
        int r3 = atomicAdd(&offsets[d.w+1], 1);
        *reinterpret_cast<int4*>(&rnk[e0]) = make_int4(r0,r1,r2,r3);
    } else {
        for (int e = e0; e < E; ++e) rnk[e] = atomicAdd(&offsets[dst[e]+1], 1);
    }
}

__global__ void scan1_kernel(int* __restrict__ data, int* __restrict__ bsums, int n){
    __shared__ int wsum[4];
    int base = blockIdx.x * SCAN_TILE + threadIdx.x*4;
    int v[4];
    #pragma unroll
    for (int j=0;j<4;++j) v[j] = (base+j < n) ? data[base+j] : 0;
    v[1]+=v[0]; v[2]+=v[1]; v[3]+=v[2];
    int lane = threadIdx.x & 63;
    int w = threadIdx.x >> 6;
    int s = v[3];
    for (int d=1; d<64; d<<=1){
        int o = __shfl_up(s, d);
        if (lane >= d) s += o;
    }
    if (lane == 63) wsum[w] = s;
    int sexc = s - v[3];
    __syncthreads();
    int woff = 0;
    for (int ww=0; ww<w; ++ww) woff += wsum[ww];
    int off = woff + sexc;
    #pragma unroll
    for (int j=0;j<4;++j) { if (base+j < n) data[base+j] = v[j] + off; }
    if (threadIdx.x == 255) bsums[blockIdx.x] = off + v[3];
}

__global__ void scan2_kernel(int* __restrict__ bsums, int nb){
    __shared__ int ws[4];
    __shared__ int carry_s;
    if (threadIdx.x == 0) carry_s = 0;
    __syncthreads();
    for (int start = 0; start < nb; start += 256){
        int i = start + (int)threadIdx.x;
        int v = (i < nb) ? bsums[i] : 0;
        int lane = threadIdx.x & 63, w = threadIdx.x >> 6;
        int s = v;
        for (int d=1; d<64; d<<=1){ int o = __shfl_up(s, d); if (lane >= d) s += o; }
        if (lane == 63) ws[w] = s;
        __syncthreads();
        int woff = 0;
        for (int ww=0; ww<w; ++ww) woff += ws[ww];
        int inc = s + woff + carry_s;
        if (i < nb) bsums[i] = inc - v;
        __syncthreads();
        if (threadIdx.x == 255) carry_s = inc;
        __syncthreads();
    }
}

__global__ void scan3_kernel(int* __restrict__ data, const int* __restrict__ bsums, int n){
    int base = blockIdx.x * SCAN_TILE + threadIdx.x*4;
    int add = bsums[blockIdx.x];
    #pragma unroll
    for (int j=0;j<4;++j){ if (base+j < n) data[base+j] += add; }
}

__global__ void fill_kernel(const int* __restrict__ src, const int* __restrict__ dst,
                            const int* __restrict__ rnk, const int* __restrict__ offsets,
                            int* __restrict__ csr, int E){
    int e0 = (blockIdx.x*blockDim.x + threadIdx.x)*4;
    if (e0 >= E) return;
    if (e0 + 4 <= E){
        int4 d = *reinterpret_cast<const int4*>(&dst[e0]);
        int4 r = *reinterpret_cast<const int4*>(&rnk[e0]);
        int4 s = *reinterpret_cast<const int4*>(&src[e0]);
        int o0 = offsets[d.x], o1 = offsets[d.y], o2 = offsets[d.z], o3 = offsets[d.w];
        csr[o0 + r.x] = s.x;
        csr[o1 + r.y] = s.y;
        csr[o2 + r.z] = s.z;
        csr[o3 + r.w] = s.w;
    } else {
        for (int e = e0; e < E; ++e) csr[offsets[dst[e]] + rnk[e]] = src[e];
    }
}

// ======== helpers ========
__device__ __forceinline__ void compute_slots(const int* __restrict__ batch, int n0, int N,
                                              int* slots, int* slotb, int* nslots_s, int t){
    if (t < 64) {
        int gn = n0 + t;
        int b = (gn < N) ? batch[gn] : -1;
        int bprev = -1;
        if (t > 0) bprev = (gn-1 < N) ? batch[gn-1] : -1;
        int flag = (t == 0 || b != bprev) ? 1 : 0;
        int s = flag;
        for (int d=1; d<64; d<<=1){ int o = __shfl_up(s, d); if (t >= d) s += o; }
        int slot = s - 1;
        slots[t] = slot;
        if (flag) slotb[slot] = b;
        if (t == 63) *nslots_s = s;
    }
}

// ---------------- fused: embed + fc MFMA + sigmoid + Y0 + self-dot + W0/U writes ----------------
// W0,U stored per node as idx = s*16+g (bf16); writes staged in LDS, fully coalesced.
__global__ __launch_bounds__(256) void embed_step0_kernel(
        const int* __restrict__ x_idx, const float* __restrict__ poi_emb,
        const short* __restrict__ wp, const float* __restrict__ fc_b,
        const short* __restrict__ zpack, const int* __restrict__ batch,
        const float* __restrict__ Ai,
        unsigned short* __restrict__ W0, unsigned short* __restrict__ U,
        unsigned long long uslice,
        float* __restrict__ pooled, int N)
{
    __shared__ __align__(16) char lbuf[64*YT_PITCH*2];      // xs[64][136] -> ytr[64][170]
    __shared__ __align__(16) unsigned short ubuf[64*UB_PITCH];
    __shared__ float accs[64][G_HID];
    __shared__ int slots[64];
    __shared__ int slotb[64];
    __shared__ int nslots_s;
    unsigned short* xs  = (unsigned short*)lbuf;
    unsigned short* ytr = (unsigned short*)lbuf;
    int n0 = blockIdx.x * 64;
    int t = threadIdx.x;  // 256

    #pragma unroll
    for (int i = 0; i < 8; ++i) {
        int idx = t + i*256;
        int row = idx >> 5, c4 = (idx & 31)*4;
        int gn = n0 + row;
        float4 v = make_float4(0.f,0.f,0.f,0.f);
        if (gn < N) v = *reinterpret_cast<const float4*>(&poi_emb[(size_t)x_idx[gn]*D + c4]);
        unsigned int p0 = (unsigned int)f2bf(v.x) | ((unsigned int)f2bf(v.y) << 16);
        unsigned int p1 = (unsigned int)f2bf(v.z) | ((unsigned int)f2bf(v.w) << 16);
        *reinterpret_cast<uint2*>(&xs[row*136 + c4]) = make_uint2(p0, p1);
    }
    for (int idx = t; idx < 64*G_HID; idx += 256) ((float*)accs)[idx] = 0.f;
    compute_slots(batch, n0, N, slots, slotb, &nslots_s, t);
    __syncthreads();

    int l = t & 63, w = t >> 6, li = l & 15, q = l >> 4;
    short8 a[4];
    #pragma unroll
    for (int kt = 0; kt < 4; ++kt)
        a[kt] = *reinterpret_cast<const short8*>(&xs[(w*16 + li)*136 + kt*32 + q*8]);
    f32x4 facc[8];
    #pragma unroll
    for (int ct = 0; ct < 8; ++ct) facc[ct] = (f32x4){0.f,0.f,0.f,0.f};
    #pragma unroll
    for (int kt = 0; kt < 4; ++kt){
        #pragma unroll
        for (int ct = 0; ct < 8; ++ct){
            short8 b = reinterpret_cast<const short8*>(wp)[(kt*8 + ct)*64 + l];
            facc[ct] = __builtin_amdgcn_mfma_f32_16x16x32_bf16(a[kt], b, facc[ct], 0, 0, 0);
        }
    }
    #pragma unroll
    for (int ct = 0; ct < 8; ++ct){
        float bias = fc_b[ct*16 + li];
        #pragma unroll
        for (int r = 0; r < 4; ++r){
            int row = w*16 + q*4 + r;
            float s = (n0 + row < N) ? 1.f/(1.f + __expf(-(facc[ct][r] + bias))) : 0.f;
            xs[row*136 + ct*16 + li] = f2bf(s);
        }
    }
    __syncthreads();
    short8 bw[4];
    #pragma unroll
    for (int kt = 0; kt < 4; ++kt)
        bw[kt] = *reinterpret_cast<const short8*>(&xs[(w*16 + li)*136 + kt*32 + q*8]);
    __syncthreads();

    // Y0 = Z0 X^T -> transposed bf16 in ytr[node][g*10+s]
    #pragma unroll
    for (int t10 = 0; t10 < 10; ++t10){
        f32x4 acc = (f32x4){0.f,0.f,0.f,0.f};
        #pragma unroll
        for (int kt = 0; kt < 4; ++kt){
            short8 az = *reinterpret_cast<const short8*>(&zpack[((t10*4 + kt)*64 + l)*8]);
            acc = __builtin_amdgcn_mfma_f32_16x16x32_bf16(az, bw[kt], acc, 0, 0, 0);
        }
        int base = (w*16 + li)*YT_PITCH + t10*16 + q*4;
        *reinterpret_cast<unsigned int*>(&ytr[base])   =
            (unsigned int)f2bf(acc[0]) | ((unsigned int)f2bf(acc[1]) << 16);
        *reinterpret_cast<unsigned int*>(&ytr[base+2]) =
            (unsigned int)f2bf(acc[2]) | ((unsigned int)f2bf(acc[3]) << 16);
    }
    __syncthreads();

    // 4 passes: stage [s*16+g] slice in ubuf, then fully-coalesced 640B-row writes.
    int nd = t & 63, qg = t >> 6;             // qg = wave id (uniform per wave)
    int ndw = t >> 2, part = t & 3;           // write mapping
    int gnw = n0 + ndw;
    #pragma unroll
    for (int pass = 0; pass < 4; ++pass){
        if (pass == 0){
            #pragma unroll
            for (int i = 0; i < 4; ++i){
                int g = qg*4 + i;
                #pragma unroll
                for (int s = 0; s < S_HID; ++s)
                    ubuf[nd*UB_PITCH + s*16 + g] = ytr[nd*YT_PITCH + g*10 + s];
            }
        } else {
            const float* Aw = Ai + (size_t)(pass-1)*1600;
            #pragma unroll
            for (int i = 0; i < 4; ++i){
                int g = qg*4 + i;
                float y[10];
                #pragma unroll
                for (int tt = 0; tt < 5; ++tt){
                    unsigned int pk = *reinterpret_cast<const unsigned int*>(
                        &ytr[nd*YT_PITCH + g*10 + 2*tt]);
                    y[2*tt] = bf_lo(pk); y[2*tt+1] = bf_hi(pk);
                }
                #pragma unroll
                for (int s = 0; s < S_HID; ++s){
                    float u = 0.f;
                    #pragma unroll
                    for (int tt = 0; tt < 10; ++tt)
                        u += Aw[g*100 + s*10 + tt] * y[tt];
                    ubuf[nd*UB_PITCH + s*16 + g] = f2bf(u);
                }
            }
        }
        __syncthreads();
        if (gnw < N){
            unsigned short* dstbuf = (pass == 0) ? W0 : (U + (size_t)(pass-1)*uslice);
            uint2* dg = reinterpret_cast<uint2*>(dstbuf + (size_t)gnw*160 + part*40);
            const uint2* sl = reinterpret_cast<const uint2*>(&ubuf[ndw*UB_PITCH + part*40]);
            #pragma unroll
            for (int k2 = 0; k2 < 10; ++k2) dg[k2] = sl[k2];
        }
        __syncthreads();
    }

    // self-dot d0[g,node] -> slot pooling
    #pragma unroll
    for (int i = 0; i < 4; ++i){
        int nd2 = t & 63;
        int g = (t >> 6) + i*4;
        if (n0 + nd2 < N){
            float c = 0.f;
            #pragma unroll
            for (int s = 0; s < S_HID; ++s){
                float y = bf_lo((unsigned int)ytr[nd2*YT_PITCH + g*10 + s]);
                c += y*y;
            }
            atomicAdd(&accs[slots[nd2]][g], c);
        }
    }
    __syncthreads();
    int ns = nslots_s;
    for (int idx = t; idx < ns*G_HID; idx += 256){
        int j = idx >> 4, g = idx & 15;
        int b = slotb[j];
        if (b >= 0) atomicAdd(&pooled[(size_t)b*64 + g], accs[j][g]);
    }
}

// ---------------- per-step: W_i = prop(W_{i-1}); d = <U_i, W_i>; pool (LDS-free) ----------------
__global__ __launch_bounds__(256) void propw_kernel(
        const uint2* __restrict__ Win, uint2* __restrict__ Wout,
        const uint2* __restrict__ Ui,
        const int* __restrict__ offsets, const int* __restrict__ csr,
        const int* __restrict__ batch, float* __restrict__ pooled,
        int N, int stepoff)
{
    int t = threadIdx.x;
    int wv = t >> 6, l = t & 63;
    int v = blockIdx.x*4 + wv;
    if (v >= N) return;
    int beg = offsets[v], end = offsets[v+1];
    int lc = min(l, 39);
    float a0=0.f, a1=0.f, a2=0.f, a3=0.f;
    for (int base = beg; base < end; base += 64){
        int cnt = min(64, end - base);
        int myu = (base + l < end) ? csr[base + l] : 0;
        for (int ei = 0; ei < cnt; ei += 4){
            int u0 = __shfl(myu, ei);
            int u1 = __shfl(myu, (ei+1)&63);
            int u2 = __shfl(myu, (ei+2)&63);
            int u3 = __shfl(myu, (ei+3)&63);
            uint2 w0 = Win[(size_t)u0*40 + lc];
            uint2 w1 = Win[(size_t)u1*40 + lc];
            uint2 w2 = Win[(size_t)u2*40 + lc];
            uint2 w3 = Win[(size_t)u3*40 + lc];
            if (ei+1 >= cnt){ w1.x = 0u; w1.y = 0u; }
            if (ei+2 >= cnt){ w2.x = 0u; w2.y = 0u; }
            if (ei+3 >= cnt){ w3.x = 0u; w3.y = 0u; }
            a0 += bf_lo(w0.x) + bf_lo(w1.x) + bf_lo(w2.x) + bf_lo(w3.x);
            a1 += bf_hi(w0.x) + bf_hi(w1.x) + bf_hi(w2.x) + bf_hi(w3.x);
            a2 += bf_lo(w0.y) + bf_lo(w1.y) + bf_lo(w2.y) + bf_lo(w3.y);
            a3 += bf_hi(w0.y) + bf_hi(w1.y) + bf_hi(w2.y) + bf_hi(w3.y);
        }
    }
    uint2 uv = Ui[(size_t)v*40 + lc];
    bool act = (l < 40);
    float c0 = act ? a0*bf_lo(uv.x) : 0.f;
    float c1 = act ? a1*bf_hi(uv.x) : 0.f;
    float c2 = act ? a2*bf_lo(uv.y) : 0.f;
    float c3 = act ? a3*bf_hi(uv.y) : 0.f;
    if (act){
        uint2 o;
        o.x = (unsigned int)f2bf(a0) | ((unsigned int)f2bf(a1) << 16);
        o.y = (unsigned int)f2bf(a2) | ((unsigned int)f2bf(a3) << 16);
        Wout[(size_t)v*40 + l] = o;
    }
    #pragma unroll
    for (int m = 4; m <= 32; m <<= 1){
        c0 += __shfl_xor(c0, m);
        c1 += __shfl_xor(c1, m);
        c2 += __shfl_xor(c2, m);
        c3 += __shfl_xor(c3, m);
    }
    if (l < 4){
        int b = batch[v];
        float* pb = &pooled[(size_t)b*64 + stepoff + 4*l];
        atomicAdd(pb+0, c0);
        atomicAdd(pb+1, c1);
        atomicAdd(pb+2, c2);
        atomicAdd(pb+3, c3);
    }
}

// ---------------- out = leaky(pooled @ mlp_w + mlp_b) ----------------
__global__ void out_kernel(const float* __restrict__ pooled, const float* __restrict__ mlp_w,
                           const float* __restrict__ mlp_b, float* __restrict__ out, int B){
    __shared__ float row[64];
    int b = blockIdx.x;
    int t = threadIdx.x;  // 128
    if (t < 64) row[t] = pooled[(size_t)b*64 + t];
    __syncthreads();
    float acc = mlp_b[t];
    for (int j=0;j<64;++j) acc += row[j]*mlp_w[j*D + t];
    out[(size_t)b*D + t] = leaky_f(acc);
}

extern "C" void kernel_launch(void* const* d_in, const int* in_sizes, int n_in,
                              void* d_out, int out_size, void* d_ws, size_t ws_size,
                              hipStream_t stream)
{
    const int*   x_idx = (const int*)d_in[0];
    const int*   edge  = (const int*)d_in[1];
    const int*   batch = (const int*)d_in[2];
    const float* poi   = (const float*)d_in[3];
    const float* fc_w  = (const float*)d_in[4];
    const float* fc_b  = (const float*)d_in[5];
    const float* adj   = (const float*)d_in[6];
    const float* feat  = (const float*)d_in[7];
    const float* mlp_w = (const float*)d_in[8];
    const float* mlp_b = (const float*)d_in[9];
    float* out = (float*)d_out;

    int N = in_sizes[0];
    int E = in_sizes[1] / 2;
    int B = out_size / D;
    int sblk = (N + 63) / 64;
    size_t NP = (size_t)sblk * 64;

    char* p = (char*)d_ws;
    auto alloc = [&](size_t bytes)->char* {
        char* r = p;
        p += (bytes + 255) & ~(size_t)255;
        return r;
    };
    unsigned short* W0 = (unsigned short*)alloc(NP*160*2);
    unsigned short* Wa = (unsigned short*)alloc(NP*160*2);
    unsigned short* Wb = (unsigned short*)alloc(NP*160*2);
    unsigned short* U  = (unsigned short*)alloc((size_t)3*NP*160*2);
    float* pooled      = (float*)alloc((size_t)B*64*4);
    short* zpack       = (short*)alloc((size_t)20480*2);
    short* wp          = (short*)alloc((size_t)16384*2);
    float* Ai          = (float*)alloc((size_t)3*1600*4);
    int*   offsets     = (int*)alloc((size_t)(N+1)*4);
    int*   rnk         = (int*)alloc((size_t)E*4);
    int*   csr         = (int*)alloc((size_t)E*4);
    int*   bsums       = (int*)alloc(4096);

    const int* srcp = edge;
    const int* dstp = edge + E;

    hipMemsetAsync(offsets, 0, (size_t)(N+1)*4, stream);
    hipMemsetAsync(pooled, 0, (size_t)B*64*4, stream);

    prep_kernel<<<G_HID, 128, 0, stream>>>(adj, feat, zpack, Ai);
    wpack_kernel<<<64, 256, 0, stream>>>(fc_w, wp);

    count_kernel<<<(E/4 + 255)/256, 256, 0, stream>>>(dstp, offsets, rnk, E);
    int scan_n = N + 1;
    int nblk = (scan_n + SCAN_TILE - 1) / SCAN_TILE;
    scan1_kernel<<<nblk, 256, 0, stream>>>(offsets, bsums, scan_n);
    scan2_kernel<<<1, 256, 0, stream>>>(bsums, nblk);
    scan3_kernel<<<nblk, 256, 0, stream>>>(offsets, bsums, scan_n);
    fill_kernel<<<(E/4 + 255)/256, 256, 0, stream>>>(srcp, dstp, rnk, offsets, csr, E);

    embed_step0_kernel<<<sblk, 256, 0, stream>>>(x_idx, poi, wp, fc_b, zpack, batch,
                                                 Ai, W0, U, (unsigned long long)(NP*160),
                                                 pooled, N);

    const unsigned short* win = W0;
    unsigned short* bufs[2] = {Wa, Wb};
    for (int i = 1; i < MAX_STEP; ++i){
        unsigned short* wout = bufs[(i-1) & 1];
        propw_kernel<<<(N+3)/4, 256, 0, stream>>>(
            (const uint2*)win, (uint2*)wout,
            (const uint2*)(U + (size_t)(i-1)*NP*160),
            offsets, csr, batch, pooled, N, i*G_HID);
        win = wout;
    }
    out_kernel<<<B, D, 0, stream>>>(pooled, mlp_w, mlp_b, out, B);
}